// Round 4
// baseline (711.176 us; speedup 1.0000x reference)
//
#include <hip/hip_runtime.h>

typedef __bf16 bf16x8 __attribute__((ext_vector_type(8)));
typedef float f32x4 __attribute__((ext_vector_type(4)));
typedef unsigned short ushort_t;

#define MFMA_16x16x32(A, B, C) __builtin_amdgcn_mfma_f32_16x16x32_bf16(A, B, C, 0, 0, 0)

__device__ __forceinline__ ushort_t f2bf(float f) {
  unsigned int x;
  __builtin_memcpy(&x, &f, 4);
  x = x + 0x7fffu + ((x >> 16) & 1u);
  return (ushort_t)(x >> 16);
}
// sanitizing variant (non-finite -> 0): keeps any residual dtype surprise finite
__device__ __forceinline__ ushort_t f2bf_s(float f) {
  if (!(__builtin_fabsf(f) < 3.0e38f)) f = 0.0f;
  return f2bf(f);
}

__device__ __forceinline__ uint4 cvt8(float4 a, float4 b) {
  uint4 r;
  r.x = (unsigned)f2bf_s(a.x) | ((unsigned)f2bf_s(a.y) << 16);
  r.y = (unsigned)f2bf_s(a.z) | ((unsigned)f2bf_s(a.w) << 16);
  r.z = (unsigned)f2bf_s(b.x) | ((unsigned)f2bf_s(b.y) << 16);
  r.w = (unsigned)f2bf_s(b.z) | ((unsigned)f2bf_s(b.w) << 16);
  return r;
}

// ---------------------------------------------------------------------------
// Projection GEMM: C[m,n] = sum_k A[m,k]*B[n,k]; A,B f32 (cvt to bf16 on LDS
// stage), C bf16. 128x128 tile, BK=32, 256 thr = 4 waves (2x2).
// ---------------------------------------------------------------------------
__launch_bounds__(256)
__global__ void gemm_proj(const float* __restrict__ A, const float* __restrict__ B,
                          ushort_t* __restrict__ C, int K, int lda, int ldb, int ldc) {
  constexpr int BM = 128, BN = 128, BK = 32;
  constexpr int WM = 64, WN = 64, MR = 4, NR = 4;

  __shared__ ushort_t lA[BM * BK];
  __shared__ ushort_t lB[BN * BK];

  const int m0 = blockIdx.y * BM;
  const int n0 = blockIdx.x * BN;
  const int tid = threadIdx.x;
  const int lane = tid & 63, wid = tid >> 6;
  const int wr = wid >> 1, wc = wid & 1;

  f32x4 acc[MR][NR] = {};

  for (int k0 = 0; k0 < K; k0 += BK) {
#pragma unroll
    for (int i = 0; i < 2; ++i) {
      int idx = i * 256 + tid;
      const float* g = A + (long long)(m0 + (idx >> 2)) * lda + k0 + (idx & 3) * 8;
      *(uint4*)&lA[idx * 8] = cvt8(*(const float4*)g, *(const float4*)(g + 4));
    }
#pragma unroll
    for (int i = 0; i < 2; ++i) {
      int idx = i * 256 + tid;
      const float* g = B + (long long)(n0 + (idx >> 2)) * ldb + k0 + (idx & 3) * 8;
      *(uint4*)&lB[idx * 8] = cvt8(*(const float4*)g, *(const float4*)(g + 4));
    }
    __syncthreads();

    bf16x8 af[MR], bf[NR];
#pragma unroll
    for (int m = 0; m < MR; ++m)
      af[m] = *(const bf16x8*)&lA[(wr * WM + m * 16 + (lane & 15)) * BK + (lane >> 4) * 8];
#pragma unroll
    for (int n = 0; n < NR; ++n)
      bf[n] = *(const bf16x8*)&lB[(wc * WN + n * 16 + (lane & 15)) * BK + (lane >> 4) * 8];
#pragma unroll
    for (int m = 0; m < MR; ++m)
#pragma unroll
      for (int n = 0; n < NR; ++n)
        acc[m][n] = MFMA_16x16x32(af[m], bf[n], acc[m][n]);
    __syncthreads();
  }

#pragma unroll
  for (int m = 0; m < MR; ++m)
#pragma unroll
    for (int n = 0; n < NR; ++n)
#pragma unroll
      for (int j = 0; j < 4; ++j) {
        int row = m0 + wr * WM + m * 16 + (lane >> 4) * 4 + j;
        int col = n0 + wc * WN + n * 16 + (lane & 15);
        C[(long long)row * ldc + col] = f2bf(acc[m][n][j]);
      }
}

// ---------------------------------------------------------------------------
// V projection with transposed epilogue: A=x f32 [B*S][D], B=Wv f32 [D][D],
// output scattered to Vt [B*H][64][1024] (dk-major per head) bf16.
// ---------------------------------------------------------------------------
__launch_bounds__(256)
__global__ void gemm_vt(const float* __restrict__ A, const float* __restrict__ B,
                        ushort_t* __restrict__ Vt) {
  constexpr int BM = 128, BN = 128, BK = 32, D = 1024;
  constexpr int WM = 64, WN = 64, MR = 4, NR = 4;

  __shared__ ushort_t lA[BM * BK];
  __shared__ ushort_t lB[BN * BK];

  const int m0 = blockIdx.y * BM;
  const int n0 = blockIdx.x * BN;
  const int tid = threadIdx.x;
  const int lane = tid & 63, wid = tid >> 6;
  const int wr = wid >> 1, wc = wid & 1;

  f32x4 acc[MR][NR] = {};

  for (int k0 = 0; k0 < D; k0 += BK) {
#pragma unroll
    for (int i = 0; i < 2; ++i) {
      int idx = i * 256 + tid;
      const float* g = A + (long long)(m0 + (idx >> 2)) * D + k0 + (idx & 3) * 8;
      *(uint4*)&lA[idx * 8] = cvt8(*(const float4*)g, *(const float4*)(g + 4));
    }
#pragma unroll
    for (int i = 0; i < 2; ++i) {
      int idx = i * 256 + tid;
      const float* g = B + (long long)(n0 + (idx >> 2)) * D + k0 + (idx & 3) * 8;
      *(uint4*)&lB[idx * 8] = cvt8(*(const float4*)g, *(const float4*)(g + 4));
    }
    __syncthreads();

    bf16x8 af[MR], bf[NR];
#pragma unroll
    for (int m = 0; m < MR; ++m)
      af[m] = *(const bf16x8*)&lA[(wr * WM + m * 16 + (lane & 15)) * BK + (lane >> 4) * 8];
#pragma unroll
    for (int n = 0; n < NR; ++n)
      bf[n] = *(const bf16x8*)&lB[(wc * WN + n * 16 + (lane & 15)) * BK + (lane >> 4) * 8];
#pragma unroll
    for (int m = 0; m < MR; ++m)
#pragma unroll
      for (int n = 0; n < NR; ++n)
        acc[m][n] = MFMA_16x16x32(af[m], bf[n], acc[m][n]);
    __syncthreads();
  }

  // scatter: (row = b*1024+s, col = h*64+dk) -> Vt[(b*16+h)][dk][s]
#pragma unroll
  for (int m = 0; m < MR; ++m)
#pragma unroll
    for (int n = 0; n < NR; ++n) {
      int row = m0 + wr * WM + m * 16 + (lane >> 4) * 4;  // j=0; 4 consecutive s
      int col = n0 + wc * WN + n * 16 + (lane & 15);
      int b = row >> 10, s = row & 1023;
      int h = col >> 6, dk = col & 63;
      ushort4 pk;
      pk.x = f2bf(acc[m][n][0]);
      pk.y = f2bf(acc[m][n][1]);
      pk.z = f2bf(acc[m][n][2]);
      pk.w = f2bf(acc[m][n][3]);
      *(ushort4*)(Vt + ((long long)(b * 16 + h)) * 65536 + (long long)dk * 1024 + s) = pk;
    }
}

// ---------------------------------------------------------------------------
// Attention scores + masked softmax -> attn f32. One block = 16 q-rows of one
// (b,h). Q,K bf16 from ws.
// ---------------------------------------------------------------------------
__launch_bounds__(256)
__global__ void attn_scores(const ushort_t* __restrict__ Qp, const ushort_t* __restrict__ Kp,
                            const int* __restrict__ mask, float* __restrict__ attn) {
  constexpr int S = 1024, D = 1024;
  __shared__ float sc[16][1028];
  __shared__ ushort_t kt[64][72];

  const int q0 = blockIdx.x * 16;
  const int bh = blockIdx.y;
  const int b = bh >> 4, h = bh & 15;
  const int tid = threadIdx.x, lane = tid & 63, wid = tid >> 6;

  bf16x8 qa0, qa1;
  {
    const ushort_t* q =
        Qp + ((long long)(b * S + q0 + (lane & 15))) * D + h * 64 + (lane >> 4) * 8;
    qa0 = *(const bf16x8*)q;
    qa1 = *(const bf16x8*)(q + 32);
  }

  for (int kb = 0; kb < 16; ++kb) {
    {
      int r = tid >> 2, cg = (tid & 3) * 16;
      const ushort_t* g = Kp + ((long long)(b * S + kb * 64 + r)) * D + h * 64 + cg;
      *(uint4*)&kt[r][cg] = *(const uint4*)g;
      *(uint4*)&kt[r][cg + 8] = *(const uint4*)(g + 8);
    }
    __syncthreads();
    {
      int krow = wid * 16 + (lane & 15);
      bf16x8 b0 = *(const bf16x8*)&kt[krow][(lane >> 4) * 8];
      bf16x8 b1 = *(const bf16x8*)&kt[krow][32 + (lane >> 4) * 8];
      f32x4 acc = {};
      acc = MFMA_16x16x32(qa0, b0, acc);
      acc = MFMA_16x16x32(qa1, b1, acc);
      int key = kb * 64 + wid * 16 + (lane & 15);
      int mv = mask[b * S + key];
#pragma unroll
      for (int j = 0; j < 4; ++j)
        sc[(lane >> 4) * 4 + j][key] = mv ? acc[j] * 0.125f : -30000.0f;
    }
    __syncthreads();
  }

  for (int rr = 0; rr < 4; ++rr) {
    int r = wid * 4 + rr;
    float v[16];
    float mx = -3.0e38f;
#pragma unroll
    for (int i = 0; i < 16; ++i) {
      v[i] = sc[r][lane + i * 64];
      mx = fmaxf(mx, v[i]);
    }
#pragma unroll
    for (int off = 32; off; off >>= 1) mx = fmaxf(mx, __shfl_xor(mx, off, 64));
    float sum = 0.f;
#pragma unroll
    for (int i = 0; i < 16; ++i) {
      v[i] = __expf(v[i] - mx);
      sum += v[i];
    }
#pragma unroll
    for (int off = 32; off; off >>= 1) sum += __shfl_xor(sum, off, 64);
    float inv = 1.0f / sum;
    float* o = attn + (long long)bh * S * S + (long long)(q0 + r) * S + lane;
#pragma unroll
    for (int i = 0; i < 16; ++i) o[i * 64] = v[i] * inv;
  }
}

// ---------------------------------------------------------------------------
// PV GEMM per (b,h): A = attn f32 [S][S] (cvt on stage), B = Vt bf16
// [64][1024], C f32 written into out[b][s][h*64+dk] (head column stripe).
// BM=128, BN=64, BK=32; 4 waves 2x2 (WM=64, WN=32).
// ---------------------------------------------------------------------------
__launch_bounds__(256)
__global__ void gemm_pv(const float* __restrict__ attn, const ushort_t* __restrict__ Vt,
                        float* __restrict__ out) {
  constexpr int S = 1024, D = 1024;
  constexpr int BM = 128, BN = 64, BK = 32;
  constexpr int WM = 64, WN = 32, MR = 4, NR = 2;

  __shared__ ushort_t lA[BM * BK];
  __shared__ ushort_t lB[BN * BK];

  const int bh = blockIdx.z;
  const int b = bh >> 4, h = bh & 15;
  const float* A = attn + (long long)bh * S * S;
  const ushort_t* B = Vt + (long long)bh * 65536;
  float* C = out + (long long)b * S * D + h * 64;

  const int m0 = blockIdx.y * BM;
  const int tid = threadIdx.x;
  const int lane = tid & 63, wid = tid >> 6;
  const int wr = wid >> 1, wc = wid & 1;

  f32x4 acc[MR][NR] = {};

  for (int k0 = 0; k0 < S; k0 += BK) {
#pragma unroll
    for (int i = 0; i < 2; ++i) {
      int idx = i * 256 + tid;
      const float* g = A + (long long)(m0 + (idx >> 2)) * S + k0 + (idx & 3) * 8;
      *(uint4*)&lA[idx * 8] = cvt8(*(const float4*)g, *(const float4*)(g + 4));
    }
    {
      int row = tid >> 2, cg = (tid & 3) * 8;
      *(uint4*)&lB[row * BK + cg] = *(const uint4*)(B + (long long)row * S + k0 + cg);
    }
    __syncthreads();

    bf16x8 af[MR], bf[NR];
#pragma unroll
    for (int m = 0; m < MR; ++m)
      af[m] = *(const bf16x8*)&lA[(wr * WM + m * 16 + (lane & 15)) * BK + (lane >> 4) * 8];
#pragma unroll
    for (int n = 0; n < NR; ++n)
      bf[n] = *(const bf16x8*)&lB[(wc * WN + n * 16 + (lane & 15)) * BK + (lane >> 4) * 8];
#pragma unroll
    for (int m = 0; m < MR; ++m)
#pragma unroll
      for (int n = 0; n < NR; ++n)
        acc[m][n] = MFMA_16x16x32(af[m], bf[n], acc[m][n]);
    __syncthreads();
  }

#pragma unroll
  for (int m = 0; m < MR; ++m)
#pragma unroll
    for (int n = 0; n < NR; ++n)
#pragma unroll
      for (int j = 0; j < 4; ++j) {
        int row = m0 + wr * WM + m * 16 + (lane >> 4) * 4 + j;  // s
        int col = wc * WN + n * 16 + (lane & 15);               // dk
        C[(long long)row * D + col] = acc[m][n][j];
      }
}

// ---------------------------------------------------------------------------
// Residual + LayerNorm, IN-PLACE on out[b][s][:] (holds PV result f32).
// One block per row; reads own row + x, writes own row only.
// ---------------------------------------------------------------------------
__launch_bounds__(256)
__global__ void ln_residual(const float* __restrict__ x, const float* __restrict__ gamma,
                            const float* __restrict__ beta, float* __restrict__ out) {
  constexpr int D = 1024;
  __shared__ float red[8];
  const int row = blockIdx.x;
  const int tid = threadIdx.x, lane = tid & 63, wid = tid >> 6;
  const int d0 = tid * 4;

  float4 xv = *(const float4*)(x + (long long)row * D + d0);
  float4 ov = *(const float4*)(out + (long long)row * D + d0);
  float v[4];
  v[0] = xv.x + ov.x;
  v[1] = xv.y + ov.y;
  v[2] = xv.z + ov.z;
  v[3] = xv.w + ov.w;
  float sum = v[0] + v[1] + v[2] + v[3];
  float sq = v[0] * v[0] + v[1] * v[1] + v[2] * v[2] + v[3] * v[3];
#pragma unroll
  for (int off = 32; off; off >>= 1) {
    sum += __shfl_xor(sum, off, 64);
    sq += __shfl_xor(sq, off, 64);
  }
  if (lane == 0) {
    red[wid] = sum;
    red[4 + wid] = sq;
  }
  __syncthreads();
  sum = red[0] + red[1] + red[2] + red[3];
  sq = red[4] + red[5] + red[6] + red[7];
  const float mu = sum * (1.0f / 1024.0f);
  const float var = sq * (1.0f / 1024.0f) - mu * mu;
  const float rs = rsqrtf(var + 1e-6f);
  float4 gv = *(const float4*)(gamma + d0);
  float4 bv = *(const float4*)(beta + d0);
  float4 r;
  r.x = (v[0] - mu) * rs * gv.x + bv.x;
  r.y = (v[1] - mu) * rs * gv.y + bv.y;
  r.z = (v[2] - mu) * rs * gv.z + bv.z;
  r.w = (v[3] - mu) * rs * gv.w + bv.w;
  *(float4*)(out + (long long)row * D + d0) = r;
}

// ---------------------------------------------------------------------------
extern "C" void kernel_launch(void* const* d_in, const int* in_sizes, int n_in,
                              void* d_out, int out_size, void* d_ws, size_t ws_size,
                              hipStream_t stream) {
  const int B = 8, S = 1024, D = 1024, H = 16;
  const float* x = (const float*)d_in[0];
  const int* mask = (const int*)d_in[1];
  const float* Wq = (const float*)d_in[2];
  const float* Wk = (const float*)d_in[3];
  const float* Wv = (const float*)d_in[4];
  const float* gamma = (const float*)d_in[5];
  const float* beta = (const float*)d_in[6];

  float* attn = (float*)d_out;                     // [B*H][S][S] f32
  float* out = attn + (long long)B * H * S * S;    // [B][S][D]   f32

  const long long BSD = (long long)B * S * D;  // 8M elems
  // ws: [Qp bf16 16MB | Kp bf16 16MB]; Vt reuses Qp slot after attn_scores.
  ushort_t* Qp = (ushort_t*)d_ws;
  ushort_t* Kp = Qp + BSD;
  ushort_t* Vt = Qp;

  // Q/K projections (f32 in, bf16 out): C[m,e] = sum_d x[m,d] * W[e,d]
  gemm_proj<<<dim3(D / 128, (B * S) / 128), 256, 0, stream>>>(x, Wq, Qp, D, D, D, D);
  gemm_proj<<<dim3(D / 128, (B * S) / 128), 256, 0, stream>>>(x, Wk, Kp, D, D, D, D);

  // scores + masked softmax -> attn f32 (Output 0)
  attn_scores<<<dim3(S / 16, B * H), 256, 0, stream>>>(Qp, Kp, mask, attn);

  // V projection, scattered directly into Vt [bh][dk][s] (Qp slot, Q is dead)
  gemm_vt<<<dim3(D / 128, (B * S) / 128), 256, 0, stream>>>(x, Wv, Vt);

  // PV: out[b][s][h*64+dk] = sum_k attn[bh][s][k] * Vt[bh][dk][k]
  gemm_pv<<<dim3(1, S / 128, B * H), 256, 0, stream>>>(attn, Vt, out);

  // residual + LayerNorm in-place on out (Output 1)
  ln_residual<<<dim3(B * S), 256, 0, stream>>>(x, gamma, beta, out);
}

// Round 5
// 457.890 us; speedup vs baseline: 1.5532x; 1.5532x over previous
//
#include <hip/hip_runtime.h>

typedef __bf16 bf16x8 __attribute__((ext_vector_type(8)));
typedef float f32x4 __attribute__((ext_vector_type(4)));
typedef unsigned short ushort_t;
typedef unsigned char uchar_t;

#define MFMA_16x16x32(A, B, C) __builtin_amdgcn_mfma_f32_16x16x32_bf16(A, B, C, 0, 0, 0)

__device__ __forceinline__ float bf2f(ushort_t u) {
  unsigned int x = ((unsigned int)u) << 16;
  float f;
  __builtin_memcpy(&f, &x, 4);
  return f;
}
__device__ __forceinline__ ushort_t f2bf(float f) {
  unsigned int x;
  __builtin_memcpy(&x, &f, 4);
  x = x + 0x7fffu + ((x >> 16) & 1u);
  return (ushort_t)(x >> 16);
}
__device__ __forceinline__ ushort_t f2bf_s(float f) {
  if (!(__builtin_fabsf(f) < 3.0e38f)) f = 0.0f;
  return f2bf(f);
}

__device__ __forceinline__ void gload_lds16(const void* g, void* l) {
  __builtin_amdgcn_global_load_lds(
      (__attribute__((address_space(1))) void*)const_cast<void*>(g),
      (__attribute__((address_space(3))) void*)l, 16, 0, 0);
}

__device__ __forceinline__ uint4 cvt8(float4 a, float4 b) {
  uint4 r;
  r.x = (unsigned)f2bf_s(a.x) | ((unsigned)f2bf_s(a.y) << 16);
  r.y = (unsigned)f2bf_s(a.z) | ((unsigned)f2bf_s(a.w) << 16);
  r.z = (unsigned)f2bf_s(b.x) | ((unsigned)f2bf_s(b.y) << 16);
  r.w = (unsigned)f2bf_s(b.z) | ((unsigned)f2bf_s(b.w) << 16);
  return r;
}

// XOR-granule swizzle (granule = 8 bf16 = 16B): spreads row-column access
// across banks. sci: 64x1024 bf16 buffer; kti: 64x64 bf16 buffer.
__device__ __forceinline__ int sci(int r, int col) {
  return (r << 10) + (((((col >> 3) ^ r) & 7) << 3) | (col & 7)) + (col & ~63 & 0);
}
// NOTE: (col>>3) ranges 0..127; XOR only low 3 bits with r, keep high bits:
__device__ __forceinline__ int sci2(int r, int col) {
  int g = col >> 3;
  g = (g & ~7) | ((g ^ r) & 7);
  return (r << 10) + (g << 3) + (col & 7);
}
__device__ __forceinline__ int kti(int r, int col) {
  int g = col >> 3;
  g = (g ^ r) & 7;
  return (r << 6) + (g << 3) + (col & 7);
}

// ---------------------------------------------------------------------------
// f32 -> bf16 bulk convert (sanitizing), 4 elems/thread
// ---------------------------------------------------------------------------
__launch_bounds__(256)
__global__ void cvt_f32_bf16(const float* __restrict__ in, ushort_t* __restrict__ out, int n4) {
  int i = blockIdx.x * 256 + threadIdx.x;
  if (i >= n4) return;
  float4 v = ((const float4*)in)[i];
  ushort4 r;
  r.x = f2bf_s(v.x);
  r.y = f2bf_s(v.y);
  r.z = f2bf_s(v.z);
  r.w = f2bf_s(v.w);
  ((ushort4*)out)[i] = r;
}

// ---------------------------------------------------------------------------
// bf16 BT-GEMM (m97 structure, global_load_lds w16). C[m,n]=sum_k A[m,k]B[n,k]
// K=1024, lda=ldb=1024. SCATTER=false: C row-major bf16 [8192][1024].
// SCATTER=true: V-transpose epilogue into Vt [B*H][64][1024].
// ---------------------------------------------------------------------------
template <bool SCATTER>
__launch_bounds__(256)
__global__ void gemm_bt(const ushort_t* __restrict__ A, const ushort_t* __restrict__ B,
                        ushort_t* __restrict__ C) {
  constexpr int BK = 32, LD = 1024, K = 1024;
  constexpr int WM = 64, WN = 64, MR = 4, NR = 4;

  __shared__ ushort_t lA[128 * BK];
  __shared__ ushort_t lB[128 * BK];

  const int m0 = blockIdx.y * 128;
  const int n0 = blockIdx.x * 128;
  const int tid = threadIdx.x;
  const int lane = tid & 63, wid = tid >> 6;
  const int wr = wid >> 1, wc = wid & 1;

  f32x4 acc[MR][NR] = {};

  for (int k0 = 0; k0 < K; k0 += BK) {
#pragma unroll
    for (int i = 0; i < 2; ++i) {
      int idx = i * 256 + tid;
      const ushort_t* g = A + (long long)(m0 + (idx >> 2)) * LD + k0 + (idx & 3) * 8;
      gload_lds16(g, (void*)(lA + (i * 256 + wid * 64) * 8));
    }
#pragma unroll
    for (int i = 0; i < 2; ++i) {
      int idx = i * 256 + tid;
      const ushort_t* g = B + (long long)(n0 + (idx >> 2)) * LD + k0 + (idx & 3) * 8;
      gload_lds16(g, (void*)(lB + (i * 256 + wid * 64) * 8));
    }
    __syncthreads();

    bf16x8 af[MR], bf[NR];
#pragma unroll
    for (int m = 0; m < MR; ++m)
      af[m] = *(const bf16x8*)&lA[(wr * WM + m * 16 + (lane & 15)) * BK + (lane >> 4) * 8];
#pragma unroll
    for (int n = 0; n < NR; ++n)
      bf[n] = *(const bf16x8*)&lB[(wc * WN + n * 16 + (lane & 15)) * BK + (lane >> 4) * 8];
#pragma unroll
    for (int m = 0; m < MR; ++m)
#pragma unroll
      for (int n = 0; n < NR; ++n)
        acc[m][n] = MFMA_16x16x32(af[m], bf[n], acc[m][n]);
    __syncthreads();
  }

  if constexpr (!SCATTER) {
#pragma unroll
    for (int m = 0; m < MR; ++m)
#pragma unroll
      for (int n = 0; n < NR; ++n)
#pragma unroll
        for (int j = 0; j < 4; ++j) {
          int row = m0 + wr * WM + m * 16 + (lane >> 4) * 4 + j;
          int col = n0 + wc * WN + n * 16 + (lane & 15);
          C[(long long)row * LD + col] = f2bf(acc[m][n][j]);
        }
  } else {
#pragma unroll
    for (int m = 0; m < MR; ++m)
#pragma unroll
      for (int n = 0; n < NR; ++n) {
        int row = m0 + wr * WM + m * 16 + (lane >> 4) * 4;  // 4 consecutive s
        int col = n0 + wc * WN + n * 16 + (lane & 15);
        int b = row >> 10, s = row & 1023;
        int h = col >> 6, dk = col & 63;
        ushort4 pk;
        pk.x = f2bf(acc[m][n][0]);
        pk.y = f2bf(acc[m][n][1]);
        pk.z = f2bf(acc[m][n][2]);
        pk.w = f2bf(acc[m][n][3]);
        *(ushort4*)(C + ((long long)(b * 16 + h)) * 65536 + (long long)dk * 1024 + s) = pk;
      }
  }
}

// ---------------------------------------------------------------------------
// f32-input projection GEMM (fallback tiers) — validated round 4.
// ---------------------------------------------------------------------------
__launch_bounds__(256)
__global__ void gemm_proj(const float* __restrict__ A, const float* __restrict__ B,
                          ushort_t* __restrict__ C, int K, int lda, int ldb, int ldc) {
  constexpr int BM = 128, BN = 128, BK = 32;
  constexpr int WM = 64, WN = 64, MR = 4, NR = 4;
  __shared__ ushort_t lA[BM * BK];
  __shared__ ushort_t lB[BN * BK];
  const int m0 = blockIdx.y * BM, n0 = blockIdx.x * BN;
  const int tid = threadIdx.x, lane = tid & 63, wid = tid >> 6;
  const int wr = wid >> 1, wc = wid & 1;
  f32x4 acc[MR][NR] = {};
  for (int k0 = 0; k0 < K; k0 += BK) {
#pragma unroll
    for (int i = 0; i < 2; ++i) {
      int idx = i * 256 + tid;
      const float* g = A + (long long)(m0 + (idx >> 2)) * lda + k0 + (idx & 3) * 8;
      *(uint4*)&lA[idx * 8] = cvt8(*(const float4*)g, *(const float4*)(g + 4));
    }
#pragma unroll
    for (int i = 0; i < 2; ++i) {
      int idx = i * 256 + tid;
      const float* g = B + (long long)(n0 + (idx >> 2)) * ldb + k0 + (idx & 3) * 8;
      *(uint4*)&lB[idx * 8] = cvt8(*(const float4*)g, *(const float4*)(g + 4));
    }
    __syncthreads();
    bf16x8 af[MR], bf[NR];
#pragma unroll
    for (int m = 0; m < MR; ++m)
      af[m] = *(const bf16x8*)&lA[(wr * WM + m * 16 + (lane & 15)) * BK + (lane >> 4) * 8];
#pragma unroll
    for (int n = 0; n < NR; ++n)
      bf[n] = *(const bf16x8*)&lB[(wc * WN + n * 16 + (lane & 15)) * BK + (lane >> 4) * 8];
#pragma unroll
    for (int m = 0; m < MR; ++m)
#pragma unroll
      for (int n = 0; n < NR; ++n)
        acc[m][n] = MFMA_16x16x32(af[m], bf[n], acc[m][n]);
    __syncthreads();
  }
#pragma unroll
  for (int m = 0; m < MR; ++m)
#pragma unroll
    for (int n = 0; n < NR; ++n)
#pragma unroll
      for (int j = 0; j < 4; ++j) {
        int row = m0 + wr * WM + m * 16 + (lane >> 4) * 4 + j;
        int col = n0 + wc * WN + n * 16 + (lane & 15);
        C[(long long)row * ldc + col] = f2bf(acc[m][n][j]);
      }
}

// f32-input V projection with transpose-scatter epilogue — validated round 4.
__launch_bounds__(256)
__global__ void gemm_vt(const float* __restrict__ A, const float* __restrict__ B,
                        ushort_t* __restrict__ Vt) {
  constexpr int BM = 128, BN = 128, BK = 32, D = 1024;
  constexpr int WM = 64, WN = 64, MR = 4, NR = 4;
  __shared__ ushort_t lA[BM * BK];
  __shared__ ushort_t lB[BN * BK];
  const int m0 = blockIdx.y * BM, n0 = blockIdx.x * BN;
  const int tid = threadIdx.x, lane = tid & 63, wid = tid >> 6;
  const int wr = wid >> 1, wc = wid & 1;
  f32x4 acc[MR][NR] = {};
  for (int k0 = 0; k0 < D; k0 += BK) {
#pragma unroll
    for (int i = 0; i < 2; ++i) {
      int idx = i * 256 + tid;
      const float* g = A + (long long)(m0 + (idx >> 2)) * D + k0 + (idx & 3) * 8;
      *(uint4*)&lA[idx * 8] = cvt8(*(const float4*)g, *(const float4*)(g + 4));
    }
#pragma unroll
    for (int i = 0; i < 2; ++i) {
      int idx = i * 256 + tid;
      const float* g = B + (long long)(n0 + (idx >> 2)) * D + k0 + (idx & 3) * 8;
      *(uint4*)&lB[idx * 8] = cvt8(*(const float4*)g, *(const float4*)(g + 4));
    }
    __syncthreads();
    bf16x8 af[MR], bf[NR];
#pragma unroll
    for (int m = 0; m < MR; ++m)
      af[m] = *(const bf16x8*)&lA[(wr * WM + m * 16 + (lane & 15)) * BK + (lane >> 4) * 8];
#pragma unroll
    for (int n = 0; n < NR; ++n)
      bf[n] = *(const bf16x8*)&lB[(wc * WN + n * 16 + (lane & 15)) * BK + (lane >> 4) * 8];
#pragma unroll
    for (int m = 0; m < MR; ++m)
#pragma unroll
      for (int n = 0; n < NR; ++n)
        acc[m][n] = MFMA_16x16x32(af[m], bf[n], acc[m][n]);
    __syncthreads();
  }
#pragma unroll
  for (int m = 0; m < MR; ++m)
#pragma unroll
    for (int n = 0; n < NR; ++n) {
      int row = m0 + wr * WM + m * 16 + (lane >> 4) * 4;
      int col = n0 + wc * WN + n * 16 + (lane & 15);
      int b = row >> 10, s = row & 1023;
      int h = col >> 6, dk = col & 63;
      ushort4 pk;
      pk.x = f2bf(acc[m][n][0]);
      pk.y = f2bf(acc[m][n][1]);
      pk.z = f2bf(acc[m][n][2]);
      pk.w = f2bf(acc[m][n][3]);
      *(ushort4*)(Vt + ((long long)(b * 16 + h)) * 65536 + (long long)dk * 1024 + s) = pk;
    }
}

// ---------------------------------------------------------------------------
// FUSED attention: QK^T + masked softmax + attn f32 write + PV + out write.
// One block = 64 q-rows of one (b,h). 1024 threads = 16 waves (4 q-sub x 4).
// Scores held bf16 in XOR-swizzled LDS; softmax via 3 LDS passes + shfl.
// ---------------------------------------------------------------------------
__launch_bounds__(1024, 4)
__global__ void fused_attn(const ushort_t* __restrict__ Qp, const ushort_t* __restrict__ Kp,
                           const ushort_t* __restrict__ Vt, const int* __restrict__ mask,
                           float* __restrict__ attn, float* __restrict__ out) {
  constexpr int S = 1024, D = 1024;
  __shared__ ushort_t sc[64 * 1024];  // 128 KB swizzled score/P buffer
  __shared__ ushort_t kt[64 * 64];    // 8 KB K/V chunk staging (swizzled)
  __shared__ uchar_t ms[1024];        // mask row

  const int q0 = blockIdx.x * 64;
  const int bh = blockIdx.y, b = bh >> 4, h = bh & 15;
  const int t = threadIdx.x, lane = t & 63, w = t >> 6;
  const int mh = w >> 2, kq = w & 3;

  if (t < 256) {
    int4 mv = ((const int4*)(mask + b * S))[t];
    ms[t * 4 + 0] = (uchar_t)mv.x;
    ms[t * 4 + 1] = (uchar_t)mv.y;
    ms[t * 4 + 2] = (uchar_t)mv.z;
    ms[t * 4 + 3] = (uchar_t)mv.w;
  }

  // Q fragment: q row = q0 + mh*16 + (lane&15), dk slice (lane>>4)*8 (+32)
  bf16x8 qa0, qa1;
  {
    const ushort_t* q =
        Qp + ((long long)(b * S + q0 + mh * 16 + (lane & 15))) * D + h * 64 + (lane >> 4) * 8;
    qa0 = *(const bf16x8*)q;
    qa1 = *(const bf16x8*)(q + 32);
  }

  const int strow = t >> 4, stc4 = (t & 15) * 4;  // staging: row 0..63, col*4

  // ---- Phase 1: QK^T over 16 key-chunks of 64 ----
  for (int kb = 0; kb < 16; ++kb) {
    *(uint2*)&kt[kti(strow, stc4)] =
        *(const uint2*)(Kp + ((long long)(b * S + kb * 64 + strow)) * D + h * 64 + stc4);
    __syncthreads();
    {
      int krow = kq * 16 + (lane & 15);
      bf16x8 b0 = *(const bf16x8*)&kt[kti(krow, (lane >> 4) * 8)];
      bf16x8 b1 = *(const bf16x8*)&kt[kti(krow, 32 + (lane >> 4) * 8)];
      f32x4 acc = {};
      acc = MFMA_16x16x32(qa0, b0, acc);
      acc = MFMA_16x16x32(qa1, b1, acc);
      int key = kb * 64 + krow;
      bool valid = ms[key] != 0;
#pragma unroll
      for (int j = 0; j < 4; ++j) {
        float sv = valid ? acc[j] * 0.125f : -30000.0f;
        sc[sci2(mh * 16 + (lane >> 4) * 4 + j, key)] = f2bf(sv);
      }
    }
    __syncthreads();
  }

  // ---- Phase 2: softmax (3 passes). thread (r = t>>4, c = t&15) ----
  {
    const int r = strow, c = t & 15;
    float m = -3.0e38f;
#pragma unroll
    for (int i = 0; i < 16; ++i) {
      ushort4 sv = *(const ushort4*)&sc[sci2(r, c * 4 + i * 64)];
      m = fmaxf(m, fmaxf(fmaxf(bf2f(sv.x), bf2f(sv.y)), fmaxf(bf2f(sv.z), bf2f(sv.w))));
    }
#pragma unroll
    for (int off = 8; off; off >>= 1) m = fmaxf(m, __shfl_xor(m, off, 64));

    float sum = 0.f;
#pragma unroll
    for (int i = 0; i < 16; ++i) {
      int idx = sci2(r, c * 4 + i * 64);
      ushort4 sv = *(const ushort4*)&sc[idx];
      float p0 = __expf(bf2f(sv.x) - m);
      float p1 = __expf(bf2f(sv.y) - m);
      float p2 = __expf(bf2f(sv.z) - m);
      float p3 = __expf(bf2f(sv.w) - m);
      sum += (p0 + p1) + (p2 + p3);
      ushort4 pv;
      pv.x = f2bf(p0);
      pv.y = f2bf(p1);
      pv.z = f2bf(p2);
      pv.w = f2bf(p3);
      *(ushort4*)&sc[idx] = pv;
    }
#pragma unroll
    for (int off = 8; off; off >>= 1) sum += __shfl_xor(sum, off, 64);
    float inv = 1.0f / sum;

    float* arow = attn + ((long long)bh << 20) + ((long long)(q0 + r) << 10);
#pragma unroll
    for (int i = 0; i < 16; ++i) {
      int idx = sci2(r, c * 4 + i * 64);
      ushort4 pv = *(const ushort4*)&sc[idx];
      float4 o;
      o.x = bf2f(pv.x) * inv;
      o.y = bf2f(pv.y) * inv;
      o.z = bf2f(pv.z) * inv;
      o.w = bf2f(pv.w) * inv;
      *(float4*)&arow[c * 4 + i * 64] = o;
      pv.x = f2bf(o.x);
      pv.y = f2bf(o.y);
      pv.z = f2bf(o.z);
      pv.w = f2bf(o.w);
      *(ushort4*)&sc[idx] = pv;
    }
  }
  __syncthreads();

  // ---- Phase 3: PV. wave (qh=mh, dq=kq): O[16q x 16dk], K-loop 16x64 ----
  {
    f32x4 acc = {};
    for (int kc = 0; kc < 16; ++kc) {
      *(uint2*)&kt[kti(strow, stc4)] =
          *(const uint2*)(Vt + ((long long)bh << 16) + (strow << 10) + kc * 64 + stc4);
      __syncthreads();
      int vrow = kq * 16 + (lane & 15);
      bf16x8 vb0 = *(const bf16x8*)&kt[kti(vrow, (lane >> 4) * 8)];
      bf16x8 vb1 = *(const bf16x8*)&kt[kti(vrow, 32 + (lane >> 4) * 8)];
      int qrow = mh * 16 + (lane & 15);
      bf16x8 pa0 = *(const bf16x8*)&sc[sci2(qrow, kc * 64 + (lane >> 4) * 8)];
      bf16x8 pa1 = *(const bf16x8*)&sc[sci2(qrow, kc * 64 + 32 + (lane >> 4) * 8)];
      acc = MFMA_16x16x32(pa0, vb0, acc);
      acc = MFMA_16x16x32(pa1, vb1, acc);
      __syncthreads();
    }
    float* obase = out + ((long long)b << 20) + ((long long)(q0 + mh * 16) << 10) + h * 64 +
                   kq * 16 + (lane & 15);
#pragma unroll
    for (int j = 0; j < 4; ++j) obase[(long long)(((lane >> 4) * 4 + j)) << 10] = acc[j];
  }
}

// ---------------------------------------------------------------------------
// Tier-C kernels (validated round 4): attn_scores f32 + gemm_pv
// ---------------------------------------------------------------------------
__launch_bounds__(256)
__global__ void attn_scores(const ushort_t* __restrict__ Qp, const ushort_t* __restrict__ Kp,
                            const int* __restrict__ mask, float* __restrict__ attn) {
  constexpr int S = 1024, D = 1024;
  __shared__ float scl[16][1028];
  __shared__ ushort_t ktl[64][72];
  const int q0 = blockIdx.x * 16;
  const int bh = blockIdx.y, b = bh >> 4, h = bh & 15;
  const int tid = threadIdx.x, lane = tid & 63, wid = tid >> 6;
  bf16x8 qa0, qa1;
  {
    const ushort_t* q =
        Qp + ((long long)(b * S + q0 + (lane & 15))) * D + h * 64 + (lane >> 4) * 8;
    qa0 = *(const bf16x8*)q;
    qa1 = *(const bf16x8*)(q + 32);
  }
  for (int kb = 0; kb < 16; ++kb) {
    {
      int r = tid >> 2, cg = (tid & 3) * 16;
      const ushort_t* g = Kp + ((long long)(b * S + kb * 64 + r)) * D + h * 64 + cg;
      *(uint4*)&ktl[r][cg] = *(const uint4*)g;
      *(uint4*)&ktl[r][cg + 8] = *(const uint4*)(g + 8);
    }
    __syncthreads();
    {
      int krow = wid * 16 + (lane & 15);
      bf16x8 b0 = *(const bf16x8*)&ktl[krow][(lane >> 4) * 8];
      bf16x8 b1 = *(const bf16x8*)&ktl[krow][32 + (lane >> 4) * 8];
      f32x4 acc = {};
      acc = MFMA_16x16x32(qa0, b0, acc);
      acc = MFMA_16x16x32(qa1, b1, acc);
      int key = kb * 64 + wid * 16 + (lane & 15);
      int mv = mask[b * S + key];
#pragma unroll
      for (int j = 0; j < 4; ++j)
        scl[(lane >> 4) * 4 + j][key] = mv ? acc[j] * 0.125f : -30000.0f;
    }
    __syncthreads();
  }
  for (int rr = 0; rr < 4; ++rr) {
    int r = wid * 4 + rr;
    float v[16];
    float mx = -3.0e38f;
#pragma unroll
    for (int i = 0; i < 16; ++i) {
      v[i] = scl[r][lane + i * 64];
      mx = fmaxf(mx, v[i]);
    }
#pragma unroll
    for (int off = 32; off; off >>= 1) mx = fmaxf(mx, __shfl_xor(mx, off, 64));
    float sum = 0.f;
#pragma unroll
    for (int i = 0; i < 16; ++i) {
      v[i] = __expf(v[i] - mx);
      sum += v[i];
    }
#pragma unroll
    for (int off = 32; off; off >>= 1) sum += __shfl_xor(sum, off, 64);
    float inv = 1.0f / sum;
    float* o = attn + (long long)bh * S * S + (long long)(q0 + r) * S + lane;
#pragma unroll
    for (int i = 0; i < 16; ++i) o[i * 64] = v[i] * inv;
  }
}

__launch_bounds__(256)
__global__ void gemm_pv(const float* __restrict__ attn, const ushort_t* __restrict__ Vt,
                        float* __restrict__ out) {
  constexpr int S = 1024, D = 1024;
  constexpr int BM = 128, BK = 32;
  constexpr int WM = 64, WN = 32, MR = 4, NR = 2;
  __shared__ ushort_t lA[BM * BK];
  __shared__ ushort_t lB[64 * BK];
  const int bh = blockIdx.z, b = bh >> 4, h = bh & 15;
  const float* A = attn + (long long)bh * S * S;
  const ushort_t* B = Vt + (long long)bh * 65536;
  float* C = out + (long long)b * S * D + h * 64;
  const int m0 = blockIdx.y * BM;
  const int tid = threadIdx.x, lane = tid & 63, wid = tid >> 6;
  const int wr = wid >> 1, wc = wid & 1;
  f32x4 acc[MR][NR] = {};
  for (int k0 = 0; k0 < S; k0 += BK) {
#pragma unroll
    for (int i = 0; i < 2; ++i) {
      int idx = i * 256 + tid;
      const float* g = A + (long long)(m0 + (idx >> 2)) * S + k0 + (idx & 3) * 8;
      *(uint4*)&lA[idx * 8] = cvt8(*(const float4*)g, *(const float4*)(g + 4));
    }
    {
      int row = tid >> 2, cg = (tid & 3) * 8;
      *(uint4*)&lB[row * BK + cg] = *(const uint4*)(B + (long long)row * S + k0 + cg);
    }
    __syncthreads();
    bf16x8 af[MR], bf[NR];
#pragma unroll
    for (int m = 0; m < MR; ++m)
      af[m] = *(const bf16x8*)&lA[(wr * WM + m * 16 + (lane & 15)) * BK + (lane >> 4) * 8];
#pragma unroll
    for (int n = 0; n < NR; ++n)
      bf[n] = *(const bf16x8*)&lB[(wc * WN + n * 16 + (lane & 15)) * BK + (lane >> 4) * 8];
#pragma unroll
    for (int m = 0; m < MR; ++m)
#pragma unroll
      for (int n = 0; n < NR; ++n)
        acc[m][n] = MFMA_16x16x32(af[m], bf[n], acc[m][n]);
    __syncthreads();
  }
#pragma unroll
  for (int m = 0; m < MR; ++m)
#pragma unroll
    for (int n = 0; n < NR; ++n)
#pragma unroll
      for (int j = 0; j < 4; ++j) {
        int row = m0 + wr * WM + m * 16 + (lane >> 4) * 4 + j;
        int col = wc * WN + n * 16 + (lane & 15);
        C[(long long)row * D + col] = acc[m][n][j];
      }
}

// ---------------------------------------------------------------------------
// Residual + LayerNorm, in-place on out (f32).
// ---------------------------------------------------------------------------
__launch_bounds__(256)
__global__ void ln_residual(const float* __restrict__ x, const float* __restrict__ gamma,
                            const float* __restrict__ beta, float* __restrict__ out) {
  constexpr int D = 1024;
  __shared__ float red[8];
  const int row = blockIdx.x;
  const int tid = threadIdx.x, lane = tid & 63, wid = tid >> 6;
  const int d0 = tid * 4;
  float4 xv = *(const float4*)(x + (long long)row * D + d0);
  float4 ov = *(const float4*)(out + (long long)row * D + d0);
  float v[4];
  v[0] = xv.x + ov.x;
  v[1] = xv.y + ov.y;
  v[2] = xv.z + ov.z;
  v[3] = xv.w + ov.w;
  float sum = v[0] + v[1] + v[2] + v[3];
  float sq = v[0] * v[0] + v[1] * v[1] + v[2] * v[2] + v[3] * v[3];
#pragma unroll
  for (int off = 32; off; off >>= 1) {
    sum += __shfl_xor(sum, off, 64);
    sq += __shfl_xor(sq, off, 64);
  }
  if (lane == 0) {
    red[wid] = sum;
    red[4 + wid] = sq;
  }
  __syncthreads();
  sum = red[0] + red[1] + red[2] + red[3];
  sq = red[4] + red[5] + red[6] + red[7];
  const float mu = sum * (1.0f / 1024.0f);
  const float var = sq * (1.0f / 1024.0f) - mu * mu;
  const float rs = rsqrtf(var + 1e-6f);
  float4 gv = *(const float4*)(gamma + d0);
  float4 bv = *(const float4*)(beta + d0);
  float4 r;
  r.x = (v[0] - mu) * rs * gv.x + bv.x;
  r.y = (v[1] - mu) * rs * gv.y + bv.y;
  r.z = (v[2] - mu) * rs * gv.z + bv.z;
  r.w = (v[3] - mu) * rs * gv.w + bv.w;
  *(float4*)(out + (long long)row * D + d0) = r;
}

// ---------------------------------------------------------------------------
extern "C" void kernel_launch(void* const* d_in, const int* in_sizes, int n_in,
                              void* d_out, int out_size, void* d_ws, size_t ws_size,
                              hipStream_t stream) {
  const int B = 8, S = 1024, D = 1024, H = 16;
  const float* x = (const float*)d_in[0];
  const int* mask = (const int*)d_in[1];
  const float* Wq = (const float*)d_in[2];
  const float* Wk = (const float*)d_in[3];
  const float* Wv = (const float*)d_in[4];
  const float* gamma = (const float*)d_in[5];
  const float* beta = (const float*)d_in[6];

  float* attn = (float*)d_out;
  float* out = attn + (long long)B * H * S * S;

  const long long BSD = (long long)B * S * D;
  const long long DDe = (long long)D * D;
  const size_t MB = 1u << 20;
  ushort_t* ws = (ushort_t*)d_ws;

  if (ws_size >= 70 * MB) {
    // Tier A: all-bf16 (m97 gload GEMMs)
    ushort_t* xb = ws;               // 16 MB
    ushort_t* Wqb = xb + BSD;        // 2 MB
    ushort_t* Wkb = Wqb + DDe;       // 2 MB
    ushort_t* Wvb = Wkb + DDe;       // 2 MB
    ushort_t* Qp = Wvb + DDe;        // 16 MB
    ushort_t* Kp = Qp + BSD;         // 16 MB
    ushort_t* Vt = Kp + BSD;         // 16 MB
    cvt_f32_bf16<<<dim3((int)(BSD / 4 / 256)), 256, 0, stream>>>(x, xb, (int)(BSD / 4));
    cvt_f32_bf16<<<dim3((int)(DDe / 4 / 256)), 256, 0, stream>>>(Wq, Wqb, (int)(DDe / 4));
    cvt_f32_bf16<<<dim3((int)(DDe / 4 / 256)), 256, 0, stream>>>(Wk, Wkb, (int)(DDe / 4));
    cvt_f32_bf16<<<dim3((int)(DDe / 4 / 256)), 256, 0, stream>>>(Wv, Wvb, (int)(DDe / 4));
    gemm_bt<false><<<dim3(D / 128, (B * S) / 128), 256, 0, stream>>>(xb, Wqb, Qp);
    gemm_bt<false><<<dim3(D / 128, (B * S) / 128), 256, 0, stream>>>(xb, Wkb, Kp);
    gemm_bt<true><<<dim3(D / 128, (B * S) / 128), 256, 0, stream>>>(xb, Wvb, Vt);
    fused_attn<<<dim3(S / 64, B * H), 1024, 0, stream>>>(Qp, Kp, Vt, mask, attn, out);
    ln_residual<<<dim3(B * S), 256, 0, stream>>>(x, gamma, beta, out);
  } else if (ws_size >= 48 * MB) {
    // Tier B: f32-staged projections + fused attention
    ushort_t* Qp = ws;
    ushort_t* Kp = Qp + BSD;
    ushort_t* Vt = Kp + BSD;
    gemm_proj<<<dim3(D / 128, (B * S) / 128), 256, 0, stream>>>(x, Wq, Qp, D, D, D, D);
    gemm_proj<<<dim3(D / 128, (B * S) / 128), 256, 0, stream>>>(x, Wk, Kp, D, D, D, D);
    gemm_vt<<<dim3(D / 128, (B * S) / 128), 256, 0, stream>>>(x, Wv, Vt);
    fused_attn<<<dim3(S / 64, B * H), 1024, 0, stream>>>(Qp, Kp, Vt, mask, attn, out);
    ln_residual<<<dim3(B * S), 256, 0, stream>>>(x, gamma, beta, out);
  } else {
    // Tier C: validated round-4 pipeline
    ushort_t* Qp = ws;
    ushort_t* Kp = Qp + BSD;
    ushort_t* Vt = Qp;  // reuse after attn_scores
    gemm_proj<<<dim3(D / 128, (B * S) / 128), 256, 0, stream>>>(x, Wq, Qp, D, D, D, D);
    gemm_proj<<<dim3(D / 128, (B * S) / 128), 256, 0, stream>>>(x, Wk, Kp, D, D, D, D);
    attn_scores<<<dim3(S / 16, B * H), 256, 0, stream>>>(Qp, Kp, mask, attn);
    gemm_vt<<<dim3(D / 128, (B * S) / 128), 256, 0, stream>>>(x, Wv, Vt);
    gemm_pv<<<dim3(1, S / 128, B * H), 256, 0, stream>>>(attn, Vt, out);
    ln_residual<<<dim3(B * S), 256, 0, stream>>>(x, gamma, beta, out);
  }
}

// Round 6
// 409.960 us; speedup vs baseline: 1.7347x; 1.1169x over previous
//
#include <hip/hip_runtime.h>

typedef __bf16 bf16x8 __attribute__((ext_vector_type(8)));
typedef float f32x4 __attribute__((ext_vector_type(4)));
typedef unsigned short ushort_t;
typedef unsigned char uchar_t;

#define MFMA_16x16x32(A, B, C) __builtin_amdgcn_mfma_f32_16x16x32_bf16(A, B, C, 0, 0, 0)

__device__ __forceinline__ float bf2f(ushort_t u) {
  unsigned int x = ((unsigned int)u) << 16;
  float f;
  __builtin_memcpy(&f, &x, 4);
  return f;
}
__device__ __forceinline__ ushort_t f2bf(float f) {
  unsigned int x;
  __builtin_memcpy(&x, &f, 4);
  x = x + 0x7fffu + ((x >> 16) & 1u);
  return (ushort_t)(x >> 16);
}
__device__ __forceinline__ ushort_t f2bf_s(float f) {
  if (!(__builtin_fabsf(f) < 3.0e38f)) f = 0.0f;
  return f2bf(f);
}

__device__ __forceinline__ void gload_lds16(const void* g, void* l) {
  __builtin_amdgcn_global_load_lds(
      (__attribute__((address_space(1))) void*)const_cast<void*>(g),
      (__attribute__((address_space(3))) void*)l, 16, 0, 0);
}

__device__ __forceinline__ uint4 cvt8(float4 a, float4 b) {
  uint4 r;
  r.x = (unsigned)f2bf_s(a.x) | ((unsigned)f2bf_s(a.y) << 16);
  r.y = (unsigned)f2bf_s(a.z) | ((unsigned)f2bf_s(a.w) << 16);
  r.z = (unsigned)f2bf_s(b.x) | ((unsigned)f2bf_s(b.y) << 16);
  r.w = (unsigned)f2bf_s(b.z) | ((unsigned)f2bf_s(b.w) << 16);
  return r;
}

// XOR-granule swizzle (granule = 8 bf16 = 16B).
// sci32: [32][1024] bf16 buffer; kti: [64][64] bf16 buffer.
__device__ __forceinline__ int sci32(int r, int col) {
  int g = col >> 3;
  g = (g & ~7) | ((g ^ r) & 7);
  return (r << 10) + (g << 3) + (col & 7);
}
__device__ __forceinline__ int kti(int r, int col) {
  int g = col >> 3;
  g = (g ^ r) & 7;
  return (r << 6) + (g << 3) + (col & 7);
}

// ---------------------------------------------------------------------------
// f32 -> bf16 bulk convert (sanitizing), 4 elems/thread
// ---------------------------------------------------------------------------
__launch_bounds__(256)
__global__ void cvt_f32_bf16(const float* __restrict__ in, ushort_t* __restrict__ out, int n4) {
  int i = blockIdx.x * 256 + threadIdx.x;
  if (i >= n4) return;
  float4 v = ((const float4*)in)[i];
  ushort4 r;
  r.x = f2bf_s(v.x);
  r.y = f2bf_s(v.y);
  r.z = f2bf_s(v.z);
  r.w = f2bf_s(v.w);
  ((ushort4*)out)[i] = r;
}

// ---------------------------------------------------------------------------
// bf16 BT-GEMM (m97 structure, global_load_lds w16). C[m,n]=sum_k A[m,k]B[n,k]
// SCATTER=false: C row-major bf16. SCATTER=true: Vt [B*H][64][1024] epilogue.
// ---------------------------------------------------------------------------
template <bool SCATTER>
__launch_bounds__(256)
__global__ void gemm_bt(const ushort_t* __restrict__ A, const ushort_t* __restrict__ B,
                        ushort_t* __restrict__ C) {
  constexpr int BK = 32, LD = 1024, K = 1024;
  constexpr int WM = 64, WN = 64, MR = 4, NR = 4;

  __shared__ ushort_t lA[128 * BK];
  __shared__ ushort_t lB[128 * BK];

  const int m0 = blockIdx.y * 128;
  const int n0 = blockIdx.x * 128;
  const int tid = threadIdx.x;
  const int lane = tid & 63, wid = tid >> 6;
  const int wr = wid >> 1, wc = wid & 1;

  f32x4 acc[MR][NR] = {};

  for (int k0 = 0; k0 < K; k0 += BK) {
#pragma unroll
    for (int i = 0; i < 2; ++i) {
      int idx = i * 256 + tid;
      const ushort_t* g = A + (long long)(m0 + (idx >> 2)) * LD + k0 + (idx & 3) * 8;
      gload_lds16(g, (void*)(lA + (i * 256 + wid * 64) * 8));
    }
#pragma unroll
    for (int i = 0; i < 2; ++i) {
      int idx = i * 256 + tid;
      const ushort_t* g = B + (long long)(n0 + (idx >> 2)) * LD + k0 + (idx & 3) * 8;
      gload_lds16(g, (void*)(lB + (i * 256 + wid * 64) * 8));
    }
    __syncthreads();

    bf16x8 af[MR], bf[NR];
#pragma unroll
    for (int m = 0; m < MR; ++m)
      af[m] = *(const bf16x8*)&lA[(wr * WM + m * 16 + (lane & 15)) * BK + (lane >> 4) * 8];
#pragma unroll
    for (int n = 0; n < NR; ++n)
      bf[n] = *(const bf16x8*)&lB[(wc * WN + n * 16 + (lane & 15)) * BK + (lane >> 4) * 8];
#pragma unroll
    for (int m = 0; m < MR; ++m)
#pragma unroll
      for (int n = 0; n < NR; ++n)
        acc[m][n] = MFMA_16x16x32(af[m], bf[n], acc[m][n]);
    __syncthreads();
  }

  if constexpr (!SCATTER) {
#pragma unroll
    for (int m = 0; m < MR; ++m)
#pragma unroll
      for (int n = 0; n < NR; ++n)
#pragma unroll
        for (int j = 0; j < 4; ++j) {
          int row = m0 + wr * WM + m * 16 + (lane >> 4) * 4 + j;
          int col = n0 + wc * WN + n * 16 + (lane & 15);
          C[(long long)row * LD + col] = f2bf(acc[m][n][j]);
        }
  } else {
#pragma unroll
    for (int m = 0; m < MR; ++m)
#pragma unroll
      for (int n = 0; n < NR; ++n) {
        int row = m0 + wr * WM + m * 16 + (lane >> 4) * 4;
        int col = n0 + wc * WN + n * 16 + (lane & 15);
        int b = row >> 10, s = row & 1023;
        int h = col >> 6, dk = col & 63;
        ushort4 pk;
        pk.x = f2bf(acc[m][n][0]);
        pk.y = f2bf(acc[m][n][1]);
        pk.z = f2bf(acc[m][n][2]);
        pk.w = f2bf(acc[m][n][3]);
        *(ushort4*)(C + ((long long)(b * 16 + h)) * 65536 + (long long)dk * 1024 + s) = pk;
      }
  }
}

// ---------------------------------------------------------------------------
// f32-input projection GEMM (fallback tiers) — validated round 4.
// ---------------------------------------------------------------------------
__launch_bounds__(256)
__global__ void gemm_proj(const float* __restrict__ A, const float* __restrict__ B,
                          ushort_t* __restrict__ C, int K, int lda, int ldb, int ldc) {
  constexpr int BM = 128, BN = 128, BK = 32;
  constexpr int WM = 64, WN = 64, MR = 4, NR = 4;
  __shared__ ushort_t lA[BM * BK];
  __shared__ ushort_t lB[BN * BK];
  const int m0 = blockIdx.y * BM, n0 = blockIdx.x * BN;
  const int tid = threadIdx.x, lane = tid & 63, wid = tid >> 6;
  const int wr = wid >> 1, wc = wid & 1;
  f32x4 acc[MR][NR] = {};
  for (int k0 = 0; k0 < K; k0 += BK) {
#pragma unroll
    for (int i = 0; i < 2; ++i) {
      int idx = i * 256 + tid;
      const float* g = A + (long long)(m0 + (idx >> 2)) * lda + k0 + (idx & 3) * 8;
      *(uint4*)&lA[idx * 8] = cvt8(*(const float4*)g, *(const float4*)(g + 4));
    }
#pragma unroll
    for (int i = 0; i < 2; ++i) {
      int idx = i * 256 + tid;
      const float* g = B + (long long)(n0 + (idx >> 2)) * ldb + k0 + (idx & 3) * 8;
      *(uint4*)&lB[idx * 8] = cvt8(*(const float4*)g, *(const float4*)(g + 4));
    }
    __syncthreads();
    bf16x8 af[MR], bf[NR];
#pragma unroll
    for (int m = 0; m < MR; ++m)
      af[m] = *(const bf16x8*)&lA[(wr * WM + m * 16 + (lane & 15)) * BK + (lane >> 4) * 8];
#pragma unroll
    for (int n = 0; n < NR; ++n)
      bf[n] = *(const bf16x8*)&lB[(wc * WN + n * 16 + (lane & 15)) * BK + (lane >> 4) * 8];
#pragma unroll
    for (int m = 0; m < MR; ++m)
#pragma unroll
      for (int n = 0; n < NR; ++n)
        acc[m][n] = MFMA_16x16x32(af[m], bf[n], acc[m][n]);
    __syncthreads();
  }
#pragma unroll
  for (int m = 0; m < MR; ++m)
#pragma unroll
    for (int n = 0; n < NR; ++n)
#pragma unroll
      for (int j = 0; j < 4; ++j) {
        int row = m0 + wr * WM + m * 16 + (lane >> 4) * 4 + j;
        int col = n0 + wc * WN + n * 16 + (lane & 15);
        C[(long long)row * ldc + col] = f2bf(acc[m][n][j]);
      }
}

// f32-input V projection with transpose-scatter epilogue — validated round 4.
__launch_bounds__(256)
__global__ void gemm_vt(const float* __restrict__ A, const float* __restrict__ B,
                        ushort_t* __restrict__ Vt) {
  constexpr int BM = 128, BN = 128, BK = 32, D = 1024;
  constexpr int WM = 64, WN = 64, MR = 4, NR = 4;
  __shared__ ushort_t lA[BM * BK];
  __shared__ ushort_t lB[BN * BK];
  const int m0 = blockIdx.y * BM, n0 = blockIdx.x * BN;
  const int tid = threadIdx.x, lane = tid & 63, wid = tid >> 6;
  const int wr = wid >> 1, wc = wid & 1;
  f32x4 acc[MR][NR] = {};
  for (int k0 = 0; k0 < D; k0 += BK) {
#pragma unroll
    for (int i = 0; i < 2; ++i) {
      int idx = i * 256 + tid;
      const float* g = A + (long long)(m0 + (idx >> 2)) * D + k0 + (idx & 3) * 8;
      *(uint4*)&lA[idx * 8] = cvt8(*(const float4*)g, *(const float4*)(g + 4));
    }
#pragma unroll
    for (int i = 0; i < 2; ++i) {
      int idx = i * 256 + tid;
      const float* g = B + (long long)(n0 + (idx >> 2)) * D + k0 + (idx & 3) * 8;
      *(uint4*)&lB[idx * 8] = cvt8(*(const float4*)g, *(const float4*)(g + 4));
    }
    __syncthreads();
    bf16x8 af[MR], bf[NR];
#pragma unroll
    for (int m = 0; m < MR; ++m)
      af[m] = *(const bf16x8*)&lA[(wr * WM + m * 16 + (lane & 15)) * BK + (lane >> 4) * 8];
#pragma unroll
    for (int n = 0; n < NR; ++n)
      bf[n] = *(const bf16x8*)&lB[(wc * WN + n * 16 + (lane & 15)) * BK + (lane >> 4) * 8];
#pragma unroll
    for (int m = 0; m < MR; ++m)
#pragma unroll
      for (int n = 0; n < NR; ++n)
        acc[m][n] = MFMA_16x16x32(af[m], bf[n], acc[m][n]);
    __syncthreads();
  }
#pragma unroll
  for (int m = 0; m < MR; ++m)
#pragma unroll
    for (int n = 0; n < NR; ++n) {
      int row = m0 + wr * WM + m * 16 + (lane >> 4) * 4;
      int col = n0 + wc * WN + n * 16 + (lane & 15);
      int b = row >> 10, s = row & 1023;
      int h = col >> 6, dk = col & 63;
      ushort4 pk;
      pk.x = f2bf(acc[m][n][0]);
      pk.y = f2bf(acc[m][n][1]);
      pk.z = f2bf(acc[m][n][2]);
      pk.w = f2bf(acc[m][n][3]);
      *(ushort4*)(Vt + ((long long)(b * 16 + h)) * 65536 + (long long)dk * 1024 + s) = pk;
    }
}

// ---------------------------------------------------------------------------
// FUSED attention v2: QBLK=32, 512 threads (8 waves: mh 0..1 x kq 0..3),
// LDS 73 KB -> 2 blocks/CU. Register-prefetch of next K/V chunk (T14);
// softmax normalization deferred into PV epilogue via inv_s[].
// ---------------------------------------------------------------------------
__launch_bounds__(512, 2)
__global__ void fused_attn(const ushort_t* __restrict__ Qp, const ushort_t* __restrict__ Kp,
                           const ushort_t* __restrict__ Vt, const int* __restrict__ mask,
                           float* __restrict__ attn, float* __restrict__ out) {
  constexpr int S = 1024, D = 1024;
  __shared__ ushort_t sc[32 * 1024];  // 64 KB: unnormalized exp-scores (bf16)
  __shared__ ushort_t kt[64 * 64];    // 8 KB: K/V chunk staging (swizzled)
  __shared__ float inv_s[32];
  __shared__ uchar_t ms[1024];

  const int q0 = blockIdx.x * 32;
  const int bh = blockIdx.y, b = bh >> 4, h = bh & 15;
  const int t = threadIdx.x, lane = t & 63, w = t >> 6;
  const int mh = w >> 2, kq = w & 3;

  if (t < 256) {
    int4 mv = ((const int4*)(mask + b * S))[t];
    ms[t * 4 + 0] = (uchar_t)mv.x;
    ms[t * 4 + 1] = (uchar_t)mv.y;
    ms[t * 4 + 2] = (uchar_t)mv.z;
    ms[t * 4 + 3] = (uchar_t)mv.w;
  }

  // Q fragment: rows q0 + mh*16 + (lane&15), dk slice (lane>>4)*8 (+32)
  bf16x8 qa0, qa1;
  {
    const ushort_t* q =
        Qp + ((long long)(b * S + q0 + mh * 16 + (lane & 15))) * D + h * 64 + (lane >> 4) * 8;
    qa0 = *(const bf16x8*)q;
    qa1 = *(const bf16x8*)(q + 32);
  }

  // staging geometry: 512 threads, one 16B granule each over 64x64 bf16
  const int strow = t >> 3, stc8 = (t & 7) * 8;
  const ushort_t* Kbase = Kp + ((long long)(b * S + strow)) * D + h * 64 + stc8;
  const ushort_t* Vbase = Vt + ((long long)bh << 16) + (strow << 10) + stc8;

  // ---- Phase 1: QK^T over 16 key-chunks of 64 (reg-prefetch next chunk) ----
  uint4 pf = *(const uint4*)Kbase;  // chunk 0
  *(uint4*)&kt[kti(strow, stc8)] = pf;
  __syncthreads();  // kt + ms ready

  for (int kb = 0; kb < 16; ++kb) {
    if (kb < 15) pf = *(const uint4*)(Kbase + (long long)(kb + 1) * 64 * D);  // issue early
    int krow = kq * 16 + (lane & 15);
    bf16x8 b0 = *(const bf16x8*)&kt[kti(krow, (lane >> 4) * 8)];
    bf16x8 b1 = *(const bf16x8*)&kt[kti(krow, 32 + (lane >> 4) * 8)];
    f32x4 acc = {};
    acc = MFMA_16x16x32(qa0, b0, acc);
    acc = MFMA_16x16x32(qa1, b1, acc);
    int key = kb * 64 + krow;
    bool valid = ms[key] != 0;
#pragma unroll
    for (int j = 0; j < 4; ++j) {
      float sv = valid ? acc[j] * 0.125f : -30000.0f;
      sc[sci32(mh * 16 + (lane >> 4) * 4 + j, key)] = f2bf(sv);
    }
    __syncthreads();  // all reads of kt[kb] done
    if (kb < 15) *(uint4*)&kt[kti(strow, stc8)] = pf;
    __syncthreads();  // kt[kb+1] visible
  }

  // ---- Phase 2: softmax. thread (r = t>>4, c = t&15), V chunk-0 prefetch ----
  uint4 vpf = *(const uint4*)Vbase;  // hidden under softmax VALU work
  {
    const int r = t >> 4, c = t & 15;
    float m = -3.0e38f;
#pragma unroll
    for (int i = 0; i < 16; ++i) {
      ushort4 sv = *(const ushort4*)&sc[sci32(r, c * 4 + i * 64)];
      m = fmaxf(m, fmaxf(fmaxf(bf2f(sv.x), bf2f(sv.y)), fmaxf(bf2f(sv.z), bf2f(sv.w))));
    }
#pragma unroll
    for (int off = 8; off; off >>= 1) m = fmaxf(m, __shfl_xor(m, off, 64));

    float sum = 0.f;
#pragma unroll
    for (int i = 0; i < 16; ++i) {
      int idx = sci32(r, c * 4 + i * 64);
      ushort4 sv = *(const ushort4*)&sc[idx];
      float p0 = __expf(bf2f(sv.x) - m);
      float p1 = __expf(bf2f(sv.y) - m);
      float p2 = __expf(bf2f(sv.z) - m);
      float p3 = __expf(bf2f(sv.w) - m);
      sum += (p0 + p1) + (p2 + p3);
      ushort4 pv;
      pv.x = f2bf(p0);
      pv.y = f2bf(p1);
      pv.z = f2bf(p2);
      pv.w = f2bf(p3);
      *(ushort4*)&sc[idx] = pv;  // unnormalized exp, bf16
    }
#pragma unroll
    for (int off = 8; off; off >>= 1) sum += __shfl_xor(sum, off, 64);
    float inv = 1.0f / sum;
    if (c == 0) inv_s[r] = inv;

    float* arow = attn + ((long long)bh << 20) + ((long long)(q0 + r) << 10);
#pragma unroll
    for (int i = 0; i < 16; ++i) {
      ushort4 pv = *(const ushort4*)&sc[sci32(r, c * 4 + i * 64)];
      float4 o;
      o.x = bf2f(pv.x) * inv;
      o.y = bf2f(pv.y) * inv;
      o.z = bf2f(pv.z) * inv;
      o.w = bf2f(pv.w) * inv;
      *(float4*)&arow[c * 4 + i * 64] = o;
    }
  }
  __syncthreads();  // sc (exp) + inv_s finalized

  // ---- Phase 3: PV with deferred normalization ----
  *(uint4*)&kt[kti(strow, stc8)] = vpf;  // V chunk 0
  __syncthreads();
  {
    f32x4 acc = {};
    for (int kc = 0; kc < 16; ++kc) {
      if (kc < 15) vpf = *(const uint4*)(Vbase + (kc + 1) * 64);  // issue early
      int vrow = kq * 16 + (lane & 15);                           // dk row
      bf16x8 vb0 = *(const bf16x8*)&kt[kti(vrow, (lane >> 4) * 8)];
      bf16x8 vb1 = *(const bf16x8*)&kt[kti(vrow, 32 + (lane >> 4) * 8)];
      int qrow = mh * 16 + (lane & 15);
      bf16x8 pa0 = *(const bf16x8*)&sc[sci32(qrow, kc * 64 + (lane >> 4) * 8)];
      bf16x8 pa1 = *(const bf16x8*)&sc[sci32(qrow, kc * 64 + 32 + (lane >> 4) * 8)];
      acc = MFMA_16x16x32(pa0, vb0, acc);
      acc = MFMA_16x16x32(pa1, vb1, acc);
      __syncthreads();  // all reads of kt[kc] done
      if (kc < 15) *(uint4*)&kt[kti(strow, stc8)] = vpf;
      __syncthreads();
    }
    float* obase = out + ((long long)b << 20) + ((long long)(q0 + mh * 16) << 10) + h * 64 +
                   kq * 16 + (lane & 15);
#pragma unroll
    for (int j = 0; j < 4; ++j) {
      int rr = (lane >> 4) * 4 + j;
      obase[(long long)rr << 10] = acc[j] * inv_s[mh * 16 + rr];
    }
  }
}

// ---------------------------------------------------------------------------
// Tier-C kernels (validated round 4): attn_scores f32 + gemm_pv
// ---------------------------------------------------------------------------
__launch_bounds__(256)
__global__ void attn_scores(const ushort_t* __restrict__ Qp, const ushort_t* __restrict__ Kp,
                            const int* __restrict__ mask, float* __restrict__ attn) {
  constexpr int S = 1024, D = 1024;
  __shared__ float scl[16][1028];
  __shared__ ushort_t ktl[64][72];
  const int q0 = blockIdx.x * 16;
  const int bh = blockIdx.y, b = bh >> 4, h = bh & 15;
  const int tid = threadIdx.x, lane = tid & 63, wid = tid >> 6;
  bf16x8 qa0, qa1;
  {
    const ushort_t* q =
        Qp + ((long long)(b * S + q0 + (lane & 15))) * D + h * 64 + (lane >> 4) * 8;
    qa0 = *(const bf16x8*)q;
    qa1 = *(const bf16x8*)(q + 32);
  }
  for (int kb = 0; kb < 16; ++kb) {
    {
      int r = tid >> 2, cg = (tid & 3) * 16;
      const ushort_t* g = Kp + ((long long)(b * S + kb * 64 + r)) * D + h * 64 + cg;
      *(uint4*)&ktl[r][cg] = *(const uint4*)g;
      *(uint4*)&ktl[r][cg + 8] = *(const uint4*)(g + 8);
    }
    __syncthreads();
    {
      int krow = wid * 16 + (lane & 15);
      bf16x8 b0 = *(const bf16x8*)&ktl[krow][(lane >> 4) * 8];
      bf16x8 b1 = *(const bf16x8*)&ktl[krow][32 + (lane >> 4) * 8];
      f32x4 acc = {};
      acc = MFMA_16x16x32(qa0, b0, acc);
      acc = MFMA_16x16x32(qa1, b1, acc);
      int key = kb * 64 + wid * 16 + (lane & 15);
      int mv = mask[b * S + key];
#pragma unroll
      for (int j = 0; j < 4; ++j)
        scl[(lane >> 4) * 4 + j][key] = mv ? acc[j] * 0.125f : -30000.0f;
    }
    __syncthreads();
  }
  for (int rr = 0; rr < 4; ++rr) {
    int r = wid * 4 + rr;
    float v[16];
    float mx = -3.0e38f;
#pragma unroll
    for (int i = 0; i < 16; ++i) {
      v[i] = scl[r][lane + i * 64];
      mx = fmaxf(mx, v[i]);
    }
#pragma unroll
    for (int off = 32; off; off >>= 1) mx = fmaxf(mx, __shfl_xor(mx, off, 64));
    float sum = 0.f;
#pragma unroll
    for (int i = 0; i < 16; ++i) {
      v[i] = __expf(v[i] - mx);
      sum += v[i];
    }
#pragma unroll
    for (int off = 32; off; off >>= 1) sum += __shfl_xor(sum, off, 64);
    float inv = 1.0f / sum;
    float* o = attn + (long long)bh * S * S + (long long)(q0 + r) * S + lane;
#pragma unroll
    for (int i = 0; i < 16; ++i) o[i * 64] = v[i] * inv;
  }
}

__launch_bounds__(256)
__global__ void gemm_pv(const float* __restrict__ attn, const ushort_t* __restrict__ Vt,
                        float* __restrict__ out) {
  constexpr int S = 1024, D = 1024;
  constexpr int BM = 128, BK = 32;
  constexpr int WM = 64, WN = 32, MR = 4, NR = 2;
  __shared__ ushort_t lA[BM * BK];
  __shared__ ushort_t lB[64 * BK];
  const int bh = blockIdx.z, b = bh >> 4, h = bh & 15;
  const float* A = attn + (long long)bh * S * S;
  const ushort_t* B = Vt + (long long)bh * 65536;
  float* C = out + (long long)b * S * D + h * 64;
  const int m0 = blockIdx.y * BM;
  const int tid = threadIdx.x, lane = tid & 63, wid = tid >> 6;
  const int wr = wid >> 1, wc = wid & 1;
  f32x4 acc[MR][NR] = {};
  for (int k0 = 0; k0 < S; k0 += BK) {
#pragma unroll
    for (int i = 0; i < 2; ++i) {
      int idx = i * 256 + tid;
      const float* g = A + (long long)(m0 + (idx >> 2)) * S + k0 + (idx & 3) * 8;
      *(uint4*)&lA[idx * 8] = cvt8(*(const float4*)g, *(const float4*)(g + 4));
    }
    {
      int row = tid >> 2, cg = (tid & 3) * 8;
      *(uint4*)&lB[row * BK + cg] = *(const uint4*)(B + (long long)row * S + k0 + cg);
    }
    __syncthreads();
    bf16x8 af[MR], bf[NR];
#pragma unroll
    for (int m = 0; m < MR; ++m)
      af[m] = *(const bf16x8*)&lA[(wr * WM + m * 16 + (lane & 15)) * BK + (lane >> 4) * 8];
#pragma unroll
    for (int n = 0; n < NR; ++n)
      bf[n] = *(const bf16x8*)&lB[(wc * WN + n * 16 + (lane & 15)) * BK + (lane >> 4) * 8];
#pragma unroll
    for (int m = 0; m < MR; ++m)
#pragma unroll
      for (int n = 0; n < NR; ++n)
        acc[m][n] = MFMA_16x16x32(af[m], bf[n], acc[m][n]);
    __syncthreads();
  }
#pragma unroll
  for (int m = 0; m < MR; ++m)
#pragma unroll
    for (int n = 0; n < NR; ++n)
#pragma unroll
      for (int j = 0; j < 4; ++j) {
        int row = m0 + wr * WM + m * 16 + (lane >> 4) * 4 + j;
        int col = wc * WN + n * 16 + (lane & 15);
        C[(long long)row * D + col] = acc[m][n][j];
      }
}

// ---------------------------------------------------------------------------
// Residual + LayerNorm, in-place on out (f32).
// ---------------------------------------------------------------------------
__launch_bounds__(256)
__global__ void ln_residual(const float* __restrict__ x, const float* __restrict__ gamma,
                            const float* __restrict__ beta, float* __restrict__ out) {
  constexpr int D = 1024;
  __shared__ float red[8];
  const int row = blockIdx.x;
  const int tid = threadIdx.x, lane = tid & 63, wid = tid >> 6;
  const int d0 = tid * 4;
  float4 xv = *(const float4*)(x + (long long)row * D + d0);
  float4 ov = *(const float4*)(out + (long long)row * D + d0);
  float v[4];
  v[0] = xv.x + ov.x;
  v[1] = xv.y + ov.y;
  v[2] = xv.z + ov.z;
  v[3] = xv.w + ov.w;
  float sum = v[0] + v[1] + v[2] + v[3];
  float sq = v[0] * v[0] + v[1] * v[1] + v[2] * v[2] + v[3] * v[3];
#pragma unroll
  for (int off = 32; off; off >>= 1) {
    sum += __shfl_xor(sum, off, 64);
    sq += __shfl_xor(sq, off, 64);
  }
  if (lane == 0) {
    red[wid] = sum;
    red[4 + wid] = sq;
  }
  __syncthreads();
  sum = red[0] + red[1] + red[2] + red[3];
  sq = red[4] + red[5] + red[6] + red[7];
  const float mu = sum * (1.0f / 1024.0f);
  const float var = sq * (1.0f / 1024.0f) - mu * mu;
  const float rs = rsqrtf(var + 1e-6f);
  float4 gv = *(const float4*)(gamma + d0);
  float4 bv = *(const float4*)(beta + d0);
  float4 r;
  r.x = (v[0] - mu) * rs * gv.x + bv.x;
  r.y = (v[1] - mu) * rs * gv.y + bv.y;
  r.z = (v[2] - mu) * rs * gv.z + bv.z;
  r.w = (v[3] - mu) * rs * gv.w + bv.w;
  *(float4*)(out + (long long)row * D + d0) = r;
}

// ---------------------------------------------------------------------------
extern "C" void kernel_launch(void* const* d_in, const int* in_sizes, int n_in,
                              void* d_out, int out_size, void* d_ws, size_t ws_size,
                              hipStream_t stream) {
  const int B = 8, S = 1024, D = 1024, H = 16;
  const float* x = (const float*)d_in[0];
  const int* mask = (const int*)d_in[1];
  const float* Wq = (const float*)d_in[2];
  const float* Wk = (const float*)d_in[3];
  const float* Wv = (const float*)d_in[4];
  const float* gamma = (const float*)d_in[5];
  const float* beta = (const float*)d_in[6];

  float* attn = (float*)d_out;
  float* out = attn + (long long)B * H * S * S;

  const long long BSD = (long long)B * S * D;
  const long long DDe = (long long)D * D;
  const size_t MB = 1u << 20;
  ushort_t* ws = (ushort_t*)d_ws;

  if (ws_size >= 70 * MB) {
    // Tier A: all-bf16 (m97 gload GEMMs)
    ushort_t* xb = ws;
    ushort_t* Wqb = xb + BSD;
    ushort_t* Wkb = Wqb + DDe;
    ushort_t* Wvb = Wkb + DDe;
    ushort_t* Qp = Wvb + DDe;
    ushort_t* Kp = Qp + BSD;
    ushort_t* Vt = Kp + BSD;
    cvt_f32_bf16<<<dim3((int)(BSD / 4 / 256)), 256, 0, stream>>>(x, xb, (int)(BSD / 4));
    cvt_f32_bf16<<<dim3((int)(DDe / 4 / 256)), 256, 0, stream>>>(Wq, Wqb, (int)(DDe / 4));
    cvt_f32_bf16<<<dim3((int)(DDe / 4 / 256)), 256, 0, stream>>>(Wk, Wkb, (int)(DDe / 4));
    cvt_f32_bf16<<<dim3((int)(DDe / 4 / 256)), 256, 0, stream>>>(Wv, Wvb, (int)(DDe / 4));
    gemm_bt<false><<<dim3(D / 128, (B * S) / 128), 256, 0, stream>>>(xb, Wqb, Qp);
    gemm_bt<false><<<dim3(D / 128, (B * S) / 128), 256, 0, stream>>>(xb, Wkb, Kp);
    gemm_bt<true><<<dim3(D / 128, (B * S) / 128), 256, 0, stream>>>(xb, Wvb, Vt);
    fused_attn<<<dim3(S / 32, B * H), 512, 0, stream>>>(Qp, Kp, Vt, mask, attn, out);
    ln_residual<<<dim3(B * S), 256, 0, stream>>>(x, gamma, beta, out);
  } else if (ws_size >= 48 * MB) {
    // Tier B: f32-staged projections + fused attention
    ushort_t* Qp = ws;
    ushort_t* Kp = Qp + BSD;
    ushort_t* Vt = Kp + BSD;
    gemm_proj<<<dim3(D / 128, (B * S) / 128), 256, 0, stream>>>(x, Wq, Qp, D, D, D, D);
    gemm_proj<<<dim3(D / 128, (B * S) / 128), 256, 0, stream>>>(x, Wk, Kp, D, D, D, D);
    gemm_vt<<<dim3(D / 128, (B * S) / 128), 256, 0, stream>>>(x, Wv, Vt);
    fused_attn<<<dim3(S / 32, B * H), 512, 0, stream>>>(Qp, Kp, Vt, mask, attn, out);
    ln_residual<<<dim3(B * S), 256, 0, stream>>>(x, gamma, beta, out);
  } else {
    // Tier C: validated round-4 pipeline
    ushort_t* Qp = ws;
    ushort_t* Kp = Qp + BSD;
    ushort_t* Vt = Qp;
    gemm_proj<<<dim3(D / 128, (B * S) / 128), 256, 0, stream>>>(x, Wq, Qp, D, D, D, D);
    gemm_proj<<<dim3(D / 128, (B * S) / 128), 256, 0, stream>>>(x, Wk, Kp, D, D, D, D);
    attn_scores<<<dim3(S / 16, B * H), 256, 0, stream>>>(Qp, Kp, mask, attn);
    gemm_vt<<<dim3(D / 128, (B * S) / 128), 256, 0, stream>>>(x, Wv, Vt);
    gemm_pv<<<dim3(1, S / 128, B * H), 256, 0, stream>>>(attn, Vt, out);
    ln_residual<<<dim3(B * S), 256, 0, stream>>>(x, gamma, beta, out);
  }
}